// Round 5
// baseline (1136.678 us; speedup 1.0000x reference)
//
#include <hip/hip_runtime.h>
#include <math.h>

#define B_ROWS 262144
#define ROWS_PER_BLOCK 8
#define THREADS (ROWS_PER_BLOCK * 32)      // 256
#define NBLOCKS (B_ROWS / ROWS_PER_BLOCK)  // 32768

// output layout (floats)
#define BARY_OFF 0
#define EV_OFF   ((size_t)B_ROWS * 128)
#define ET_OFF   ((size_t)B_ROWS * 129)
#define EB_OFF   ((size_t)B_ROWS * 130)
#define ISO_OFF  ((size_t)B_ROWS * 131)
#define LC_OFF   ((size_t)B_ROWS * 131 + 1)
#define DEC_OFF  ((size_t)B_ROWS * 131 + 2)

typedef float vf4 __attribute__((ext_vector_type(4)));  // native vec for nt-store

// guarded reciprocal-sqrt: returns a FINITE large value for s==0 so that
// 0 * rsq stays 0 (reference computes q/(norm+1e-8) -> 0 for zero rows;
// text_bytes==0 makes t_atoms exactly 0 for ~1/256 of rows).
__device__ __forceinline__ float rsq_guard(float s) {
    return __builtin_amdgcn_rsqf(fmaxf(s, 1e-14f));
}

__device__ __forceinline__ float det4(const float* m) {
    float s0 = m[0]*m[5]  - m[1]*m[4];
    float s1 = m[0]*m[6]  - m[2]*m[4];
    float s2 = m[0]*m[7]  - m[3]*m[4];
    float s3 = m[1]*m[6]  - m[2]*m[5];
    float s4 = m[1]*m[7]  - m[3]*m[5];
    float s5 = m[2]*m[7]  - m[3]*m[6];
    float c5 = m[10]*m[15] - m[11]*m[14];
    float c4 = m[9]*m[15]  - m[11]*m[13];
    float c3 = m[9]*m[14]  - m[10]*m[13];
    float c2 = m[8]*m[15]  - m[11]*m[12];
    float c1 = m[8]*m[14]  - m[10]*m[12];
    float c0 = m[8]*m[13]  - m[9]*m[12];
    return s0*c5 - s1*c4 + s2*c3 + s3*c2 - s4*c1 + s5*c0;
}

// ws layout: [0:8) u64 packed count accumulator (c0@0, c1@21, c2@42),
//            [8:12) u32 ticket. Zeroed by hipMemsetAsync in kernel_launch.
__global__ __launch_bounds__(THREADS) void bridge_main(
    const float* __restrict__ vis, const int* __restrict__ txt,
    const float* __restrict__ Wv, const float* __restrict__ bv,
    const float* __restrict__ Wt, const float* __restrict__ bt,
    const float* __restrict__ Wd, const float* __restrict__ bd,
    float* __restrict__ out, unsigned long long* __restrict__ acc)
{
    __shared__ float smat[ROWS_PER_BLOCK][3][16];
    __shared__ int scntP;
    const int tid = threadIdx.x;
    if (tid == 0) scntP = 0;
    const int r = tid >> 5;   // row within block
    const int q = tid & 31;   // quaternion index
    const size_t row = (size_t)blockIdx.x * ROWS_PER_BLOCK + r;

    const float x0 = vis[row*3+0], x1 = vis[row*3+1], x2 = vis[row*3+2];
    const float tx = (float)txt[row];

    // vectorized weight loads (all 16B-aligned)
    float wv[12];
    ((float4*)wv)[0] = ((const float4*)Wv)[3*q+0];
    ((float4*)wv)[1] = ((const float4*)Wv)[3*q+1];
    ((float4*)wv)[2] = ((const float4*)Wv)[3*q+2];
    const float4 bv4 = ((const float4*)bv)[q];
    const float4 wt4 = ((const float4*)Wt)[q];
    const float4 bt4 = ((const float4*)bt)[q];

    float v[4], t[4], b[4];
    v[0] = fmaf(x0, wv[0], fmaf(x1, wv[1],  fmaf(x2, wv[2],  bv4.x)));
    v[1] = fmaf(x0, wv[3], fmaf(x1, wv[4],  fmaf(x2, wv[5],  bv4.y)));
    v[2] = fmaf(x0, wv[6], fmaf(x1, wv[7],  fmaf(x2, wv[8],  bv4.z)));
    v[3] = fmaf(x0, wv[9], fmaf(x1, wv[10], fmaf(x2, wv[11], bv4.w)));
    t[0] = fmaf(tx, wt4.x, bt4.x);
    t[1] = fmaf(tx, wt4.y, bt4.y);
    t[2] = fmaf(tx, wt4.z, bt4.z);
    t[3] = fmaf(tx, wt4.w, bt4.w);

    // project_to_su2 (guarded hardware rsq)
    {
        const float fv = rsq_guard(v[0]*v[0]+v[1]*v[1]+v[2]*v[2]+v[3]*v[3]);
        const float ft = rsq_guard(t[0]*t[0]+t[1]*t[1]+t[2]*t[2]+t[3]*t[3]);
        #pragma unroll
        for (int j = 0; j < 4; ++j) { v[j] *= fv; t[j] *= ft; }
    }

    // Karcher mean of 2 points: iterations are an exact no-op
    // (perp_v + perp_t = (v+t) - 2*sqrt((1+v.t)/2)*b0 = 0), so
    // barycenter = normalize(v + t).
    #pragma unroll
    for (int j = 0; j < 4; ++j) b[j] = v[j] + t[j];
    {
        const float fb = rsq_guard(b[0]*b[0]+b[1]*b[1]+b[2]*b[2]+b[3]*b[3]);
        #pragma unroll
        for (int j = 0; j < 4; ++j) b[j] *= fb;
    }

    // barycenter store (coalesced 16B, non-temporal: write-once stream)
    {
        vf4 bq = { b[0], b[1], b[2], b[3] };
        __builtin_nontemporal_store(bq, (vf4*)(out + BARY_OFF + row * 128 + 4 * q));
    }

    // decision partials across the row's 32 lanes
    const float4 wd0 = ((const float4*)Wd)[q];
    const float4 wd1 = ((const float4*)Wd)[32 + q];
    float p0 = b[0]*wd0.x + b[1]*wd0.y + b[2]*wd0.z + b[3]*wd0.w;
    float p1 = b[0]*wd1.x + b[1]*wd1.y + b[2]*wd1.z + b[3]*wd1.w;
    #pragma unroll
    for (int off = 16; off >= 1; off >>= 1) {
        p0 += __shfl_xor(p0, off, 32);
        p1 += __shfl_xor(p1, off, 32);
    }

    // stage sampled quaternions (q = 0,8,16,24) for the dets
    if ((q & 7) == 0) {
        const int k = q >> 3;
        *(float4*)&smat[r][0][k*4] = make_float4(v[0], v[1], v[2], v[3]);
        *(float4*)&smat[r][1][k*4] = make_float4(t[0], t[1], t[2], t[3]);
        *(float4*)&smat[r][2][k*4] = make_float4(b[0], b[1], b[2], b[3]);
    }
    __syncthreads();

    // one det per lane q=0(v),1(t),2(b); eta = det<0
    int e = 0;
    if (q < 3) {
        float m[16];
        const float4* mm = (const float4*)&smat[r][q][0];
        ((float4*)m)[0] = mm[0]; ((float4*)m)[1] = mm[1];
        ((float4*)m)[2] = mm[2]; ((float4*)m)[3] = mm[3];
        e = det4(m) < 0.0f ? 1 : 0;
        __builtin_nontemporal_store((float)e, out + (size_t)B_ROWS * (128 + q) + row);
    }
    const int eV = __shfl(e, 0, 32);
    const int eT = __shfl(e, 1, 32);
    const int eB = __shfl(e, 2, 32);
    if (q == 0) {
        const int pk = (eV ^ eB) | ((eT ^ eB) << 8) | ((eV ^ eT) << 16);
        if (pk) atomicAdd(&scntP, pk);
    }
    if (q == 3) __builtin_nontemporal_store(p0 + bd[0], out + DEC_OFF + row*2 + 0);
    if (q == 4) __builtin_nontemporal_store(p1 + bd[1], out + DEC_OFF + row*2 + 1);

    __syncthreads();

    if (tid == 0) {
        const int pk = scntP;
        const unsigned long long c0 = (unsigned long long)(pk & 255);
        const unsigned long long c1 = (unsigned long long)((pk >> 8) & 255);
        const unsigned long long c2 = (unsigned long long)((pk >> 16) & 255);
        // fields 21 bits wide; global totals <= 262144 < 2^21 -> no overflow
        const unsigned long long add = c0 | (c1 << 21) | (c2 << 42);
        if (add) atomicAdd(acc, add);
        __threadfence();
        unsigned int* ticket = (unsigned int*)(acc + 1);
        const unsigned int old = atomicAdd(ticket, 1u);
        if (old == NBLOCKS - 1) {
            // last block: all counts are in (fence + device-scope atomics)
            const unsigned long long tot = atomicAdd(acc, 0ULL);
            const float f0 = (float)(tot & 0x1FFFFFULL);
            const float f1 = (float)((tot >> 21) & 0x1FFFFFULL);
            const float f2 = (float)((tot >> 42) & 0x1FFFFFULL);
            out[ISO_OFF] = sqrtf(f0) + sqrtf(f1);
            out[LC_OFF]  = f2 / (float)B_ROWS;
        }
    }
}

extern "C" void kernel_launch(void* const* d_in, const int* in_sizes, int n_in,
                              void* d_out, int out_size, void* d_ws, size_t ws_size,
                              hipStream_t stream) {
    const float* vis = (const float*)d_in[0];
    const int*   txt = (const int*)d_in[1];
    const float* Wv  = (const float*)d_in[2];
    const float* bv  = (const float*)d_in[3];
    const float* Wt  = (const float*)d_in[4];
    const float* bt  = (const float*)d_in[5];
    const float* Wd  = (const float*)d_in[6];
    const float* bd  = (const float*)d_in[7];
    float* out = (float*)d_out;
    unsigned long long* acc = (unsigned long long*)d_ws;  // [acc u64][ticket u32]

    (void)hipMemsetAsync(d_ws, 0, 16, stream);
    bridge_main<<<NBLOCKS, THREADS, 0, stream>>>(vis, txt, Wv, bv, Wt, bt, Wd, bd, out, acc);
}